// Round 10
// baseline (386.750 us; speedup 1.0000x reference)
//
#include <hip/hip_runtime.h>
#include <stdint.h>

#define T_SEQ 2048
#define HIDDEN 4096
#define NHEAD 32
#define NKV 8
#define HDIM 128
#define QKVN 6144  // (32 + 2*8) * 128

typedef __bf16 bf16x8 __attribute__((ext_vector_type(8)));
typedef float f32x4 __attribute__((ext_vector_type(4)));
typedef unsigned short u16;
typedef u16 u16x8 __attribute__((ext_vector_type(8)));
typedef u16 u16x4 __attribute__((ext_vector_type(4)));

__device__ __forceinline__ u16 f2bf(float f) {
  uint32_t u = __builtin_bit_cast(uint32_t, f);
  u = (u + 0x7fffu + ((u >> 16) & 1u)) >> 16;
  return (u16)u;
}
__device__ __forceinline__ float bf2f(u16 h) {
  uint32_t u = ((uint32_t)h) << 16;
  return __builtin_bit_cast(float, u);
}

// async global->LDS, 16B per lane. LDS dest must be wave-uniform; HW adds lane*16.
__device__ __forceinline__ void gload16(const void* g, void* l) {
  __builtin_amdgcn_global_load_lds(
      (__attribute__((address_space(1))) void*)(uintptr_t)g,
      (__attribute__((address_space(3))) void*)(uintptr_t)l, 16, 0, 0);
}

// ---------------- fp32 -> bf16 convert ----------------
__global__ void cvt_f32_bf16(const float* __restrict__ in, u16* __restrict__ out, int n) {
  int i = (blockIdx.x * blockDim.x + threadIdx.x) * 4;
  int stride = gridDim.x * blockDim.x * 4;
  for (; i < n; i += stride) {
    float4 v = *(const float4*)(in + i);
    u16x4 o;
    o.x = f2bf(v.x); o.y = f2bf(v.y); o.z = f2bf(v.z); o.w = f2bf(v.w);
    *(u16x4*)(out + i) = o;
  }
}

// ---------------- RoPE (neox), in-place on bf16 qkv ----------------
__global__ void rope_kernel(u16* __restrict__ qkv, const int* __restrict__ pos) {
  int idx = blockIdx.x * blockDim.x + threadIdx.x;
  if (idx >= T_SEQ * 40 * 64) return;
  int i = idx & 63;
  int head = (idx >> 6) % 40;
  int t = idx / (40 * 64);
  int base = head < NHEAD ? head * HDIM : NHEAD * HDIM + (head - NHEAD) * HDIM;
  float p = (float)pos[t];
  float inv_freq = exp2f(-(float)i * (13.287712379549449f / 64.0f));
  float ang = p * inv_freq;
  float s, c;
  sincosf(ang, &s, &c);
  u16* p1 = qkv + (size_t)t * QKVN + base + i;
  u16* p2 = p1 + 64;
  float x1 = bf2f(*p1), x2 = bf2f(*p2);
  *p1 = f2bf(x1 * c - x2 * s);
  *p2 = f2bf(x2 * c + x1 * s);
}

// ---------------- V^T pre-transpose with kv-permuted columns ----------------
// vt[kvh][d][64-block base + c] holds V[base + kv(c)][d], where
// kv(c) = 32*(c>>5) + 16*((c>>2)&1) + 4*((c>>3)&3) + (c&3).
__global__ void vt_kernel(const u16* __restrict__ qkv, u16* __restrict__ vt) {
  __shared__ u16 tile[64][64];
  const int tid = threadIdx.x;
  const int tb = blockIdx.x;
  const int kvh = blockIdx.y >> 1;
  const int d0 = (blockIdx.y & 1) * 64;
  const u16* src = qkv + (size_t)(NHEAD + NKV) * HDIM + kvh * HDIM + d0;
#pragma unroll
  for (int g = 0; g < 2; ++g) {
    int u = g * 256 + tid;
    int t = u >> 3, ds = u & 7;
    u16x8 v = *(const u16x8*)(src + (size_t)(tb * 64 + t) * QKVN + ds * 8);
#pragma unroll
    for (int j = 0; j < 8; ++j) {
      int d = ds * 8 + j;
      tile[d][(((t >> 3) ^ (d & 7)) * 8) + (t & 7)] = v[j];
    }
  }
  __syncthreads();
  u16* dst = vt + ((size_t)kvh * HDIM + d0) * T_SEQ + tb * 64;
#pragma unroll
  for (int g = 0; g < 4; ++g) {
    int u = g * 256 + tid;
    int d = u >> 4, qd = u & 15;
    int a = qd >> 3, gg = (qd >> 1) & 3, b = qd & 1;
    int t0 = 32 * a + 16 * b + 4 * gg;
    u16x4 v = *(const u16x4*)&tile[d][(((t0 >> 3) ^ (d & 7)) * 8) + (t0 & 7)];
    *(u16x4*)(dst + (size_t)d * T_SEQ + qd * 4) = v;
  }
}

__device__ __forceinline__ void storeC(float* p, float v) { *p = v; }
__device__ __forceinline__ void storeC(u16* p, float v) { *p = f2bf(v); }
__device__ __forceinline__ f32x4 mfma16(bf16x8 a, bf16x8 b, f32x4 c) {
  return __builtin_amdgcn_mfma_f32_16x16x32_bf16(a, b, c, 0, 0, 0);
}

// -------- QKV GEMM: 128x384 tiles, 16x16 = 256 blocks (exact fill), BK=64 ---
// 8 waves (2M x 4N), per-wave 64x96 (acc 4x6). LDS 128KB: A 2x[128x64] (1
// half-tile/K-tile), B 2x[384x64] (3 half-tiles/K-tile). Stage schedule:
//   p0: stage A(v+1)->alt  [alt dead since v-1 p3, barrier-sep]
//   p1/p2/p3: stage B-half 0/1/2 of (v+2) -> cur  [cur.B read only in p0]
//   end: vmcnt(6)+barrier -> drains A(v+1); B(v+2)'s 6 loads stay in flight.
__global__ void __launch_bounds__(512, 1)
gemm_qkv(const u16* __restrict__ A, const u16* __restrict__ B,
         u16* __restrict__ C, int M, int N, int K) {
  __shared__ u16 As_[2][128 * 64];
  __shared__ u16 Bs_[2][384 * 64];

  const int tid = threadIdx.x;
  const int lane = tid & 63;
  const int w = tid >> 6;
  const int wr = w >> 2, wc = w & 3;   // 2M x 4N, per-wave 64x96
  const int l15 = lane & 15, lg = lane >> 4;

  // per-XCD rect: 16 by x 16 bx grid; XCD c8 owns 16by x 2bx (col-major in i8)
  const int c8 = blockIdx.x & 7, i8 = blockIdx.x >> 3;  // i8 0..31
  const int by = i8 & 15;
  const int bx = c8 * 2 + (i8 >> 4);
  const int bm = by * 128, bn = bx * 384;

  // staging lane invariants (pre-swizzled global source, rule #21)
  const int u_lo = w * 64 + lane, u_hi = u_lo + 512;
  const int r0 = u_lo >> 3, s0 = (u_lo & 7) ^ (r0 & 7);
  const int r1 = u_hi >> 3, s1 = (u_hi & 7) ^ (r1 & 7);
  const u16* a_s0 = A + (size_t)(bm + r0) * K + s0 * 8;
  const u16* a_s1 = A + (size_t)(bm + r1) * K + s1 * 8;
  const u16* b_s0[3];
  const u16* b_s1[3];
#pragma unroll
  for (int h = 0; h < 3; ++h) {
    b_s0[h] = B + (size_t)(bn + h * 128 + r0) * K + s0 * 8;
    b_s1[h] = B + (size_t)(bn + h * 128 + r1) * K + s1 * 8;
  }

  // read side: row&7 == l15&7 (wr*64, wc*96, mi*16, ni*16 all ≡ 0 mod 8... mod 16)
  const int ax = l15 & 7;
  const int sl0 = (lg ^ ax) * 8;
  const int sl1 = ((4 + lg) ^ ax) * 8;
  const int a_row = (wr * 64 + l15) * 64;
  const int b_row = (wc * 96 + l15) * 64;

  f32x4 acc[4][6] = {};
  bf16x8 bfr[6][2];

#define BARRIER() asm volatile("s_barrier" ::: "memory")
#define WAITBAR(n_) asm volatile("s_waitcnt vmcnt(" #n_ ")\n\ts_barrier" ::: "memory")
#define STAGE_A(t_, p_)                                                        \
  {                                                                            \
    gload16(a_s0 + (size_t)(t_) * 64, &As_[p_][w * 512]);                      \
    gload16(a_s1 + (size_t)(t_) * 64, &As_[p_][4096 + w * 512]);               \
  }
#define STAGE_B(t_, p_, h_)                                                    \
  {                                                                            \
    gload16(b_s0[h_] + (size_t)(t_) * 64, &Bs_[p_][(h_) * 8192 + w * 512]);    \
    gload16(b_s1[h_] + (size_t)(t_) * 64,                                      \
            &Bs_[p_][(h_) * 8192 + 4096 + w * 512]);                           \
  }

  // prologue: A(0),B(0) -> buf0; B(1) -> buf1; drain A0+B0, keep B1 in flight
  STAGE_A(0, 0);
  STAGE_B(0, 0, 0); STAGE_B(0, 0, 1); STAGE_B(0, 0, 2);
  STAGE_B(1, 1, 0); STAGE_B(1, 1, 1); STAGE_B(1, 1, 2);
  WAITBAR(6);

  const int NT = K >> 6;
  for (int v = 0; v < NT; ++v) {
    const int cur = v & 1, alt = cur ^ 1;
    const u16* Ac = &As_[cur][0];
    const u16* Bc = &Bs_[cur][0];
    const bool s1ok = (v + 1) < NT, s2ok = (v + 2) < NT;

#define MFMA_PH(mi_, A0_, A1_)                                                 \
    __builtin_amdgcn_s_setprio(1);                                             \
    _Pragma("unroll") for (int ni = 0; ni < 6; ++ni) {                         \
      acc[mi_][ni] = mfma16(A0_, bfr[ni][0], acc[mi_][ni]);                    \
      acc[mi_][ni] = mfma16(A1_, bfr[ni][1], acc[mi_][ni]);                    \
    }                                                                          \
    __builtin_amdgcn_s_setprio(0);

    // ---- phase 0: B-frags + mi=0 ----
    {
      if (s1ok) STAGE_A(v + 1, alt);
#pragma unroll
      for (int ni = 0; ni < 6; ++ni) {
        bfr[ni][0] = *(const bf16x8*)&Bc[b_row + ni * 1024 + sl0];
        bfr[ni][1] = *(const bf16x8*)&Bc[b_row + ni * 1024 + sl1];
      }
      bf16x8 a0 = *(const bf16x8*)&Ac[a_row + 0 * 1024 + sl0];
      bf16x8 a1 = *(const bf16x8*)&Ac[a_row + 0 * 1024 + sl1];
      BARRIER();
      MFMA_PH(0, a0, a1);
      BARRIER();
    }
    // ---- phase 1 ----
    {
      if (s2ok) STAGE_B(v + 2, cur, 0);
      bf16x8 a0 = *(const bf16x8*)&Ac[a_row + 1 * 1024 + sl0];
      bf16x8 a1 = *(const bf16x8*)&Ac[a_row + 1 * 1024 + sl1];
      BARRIER();
      MFMA_PH(1, a0, a1);
      BARRIER();
    }
    // ---- phase 2 ----
    {
      if (s2ok) STAGE_B(v + 2, cur, 1);
      bf16x8 a0 = *(const bf16x8*)&Ac[a_row + 2 * 1024 + sl0];
      bf16x8 a1 = *(const bf16x8*)&Ac[a_row + 2 * 1024 + sl1];
      BARRIER();
      MFMA_PH(2, a0, a1);
      BARRIER();
    }
    // ---- phase 3 ----
    {
      if (s2ok) STAGE_B(v + 2, cur, 2);
      bf16x8 a0 = *(const bf16x8*)&Ac[a_row + 3 * 1024 + sl0];
      bf16x8 a1 = *(const bf16x8*)&Ac[a_row + 3 * 1024 + sl1];
      BARRIER();
      MFMA_PH(3, a0, a1);
      if (s2ok) { WAITBAR(6); } else if (s1ok) { WAITBAR(0); } else { BARRIER(); }
    }
#undef MFMA_PH
  }

  // epilogue
#pragma unroll
  for (int mi = 0; mi < 4; ++mi)
#pragma unroll
    for (int ni = 0; ni < 6; ++ni)
#pragma unroll
      for (int r = 0; r < 4; ++r) {
        int row = bm + wr * 64 + mi * 16 + lg * 4 + r;
        int col = bn + wc * 96 + ni * 16 + l15;
        storeC(&C[(size_t)row * N + col], acc[mi][ni][r]);
      }
#undef STAGE_A
#undef STAGE_B
#undef WAITBAR
#undef BARRIER
}

// -------- 256x256 NT GEMM (Wo, split-K), unchanged from R9 ------------------
template <typename OutT>
__global__ void __launch_bounds__(512, 2)
gemm256(const u16* __restrict__ A, const u16* __restrict__ B,
        OutT* __restrict__ C0, OutT* __restrict__ C1,
        int N, int K, int NT, int sliceBlocks,
        int nbx, int rw, int rh) {
  __shared__ u16 As_[2][256 * 64];
  __shared__ u16 Bs_[2][256 * 64];

  const int tid = threadIdx.x;
  const int lane = tid & 63;
  const int w = tid >> 6;
  const int wr = w >> 2, wc = w & 3;
  const int l15 = lane & 15, lg = lane >> 4;

  const int bid = blockIdx.x;
  const int slice = bid / sliceBlocks;
  const int wi = bid % sliceBlocks;
  const int k0 = slice * (NT << 6);
  OutT* __restrict__ C = slice ? C1 : C0;

  const int c8 = wi & 7, i8 = wi >> 3;
  const int rpr = nbx / rw;
  const int by = (c8 / rpr) * rh + (i8 % rh);
  const int bx = (c8 % rpr) * rw + (i8 / rh);
  const int bm = by * 256, bn = bx * 256;

  const int u_lo = w * 64 + lane, u_hi = u_lo + 512;
  const int r0 = u_lo >> 3, s0 = (u_lo & 7) ^ (r0 & 7);
  const int r1 = u_hi >> 3, s1 = (u_hi & 7) ^ (r1 & 7);
  const u16* a0s0 = A + (size_t)(bm + r0) * K + k0 + s0 * 8;
  const u16* a0s1 = A + (size_t)(bm + r1) * K + k0 + s1 * 8;
  const u16* a1s0 = A + (size_t)(bm + 128 + r0) * K + k0 + s0 * 8;
  const u16* a1s1 = A + (size_t)(bm + 128 + r1) * K + k0 + s1 * 8;
  const u16* b0s0 = B + (size_t)(bn + r0) * K + k0 + s0 * 8;
  const u16* b0s1 = B + (size_t)(bn + r1) * K + k0 + s1 * 8;
  const u16* b1s0 = B + (size_t)(bn + 128 + r0) * K + k0 + s0 * 8;
  const u16* b1s1 = B + (size_t)(bn + 128 + r1) * K + k0 + s1 * 8;

  const int ax = l15 & 7;
  const int sl0 = (lg ^ ax) * 8;
  const int sl1 = ((4 + lg) ^ ax) * 8;
  const int a_row = (wr * 128 + l15) * 64;
  const int b_row = (wc * 64 + l15) * 64;

  f32x4 acc[8][4] = {};
  bf16x8 bfr[4][2];

#define BARRIER() asm volatile("s_barrier" ::: "memory")
#define WAITBAR(n_) asm volatile("s_waitcnt vmcnt(" #n_ ")\n\ts_barrier" ::: "memory")
#define STAGE_HALF(p0_, p1_, dst_, t_)                                         \
  {                                                                            \
    gload16((p0_) + (size_t)(t_) * 64, (dst_) + (size_t)w * 512);              \
    gload16((p1_) + (size_t)(t_) * 64, (dst_) + 4096 + (size_t)w * 512);       \
  }

  STAGE_HALF(a0s0, a0s1, &As_[0][0], 0);
  STAGE_HALF(a1s0, a1s1, &As_[0][8192], 0);
  STAGE_HALF(b0s0, b0s1, &Bs_[0][0], 0);
  STAGE_HALF(b1s0, b1s1, &Bs_[0][8192], 0);
  STAGE_HALF(b0s0, b0s1, &Bs_[1][0], 1);
  STAGE_HALF(b1s0, b1s1, &Bs_[1][8192], 1);
  WAITBAR(4);

  for (int v = 0; v < NT; ++v) {
    const int cur = v & 1, alt = cur ^ 1;
    const u16* Ac = &As_[cur][0];
    const u16* Bc = &Bs_[cur][0];
    const bool s1ok = (v + 1) < NT, s2ok = (v + 2) < NT;

#define MFMA_QUAD(p_, A0_, A1_, A2_, A3_)                                      \
    __builtin_amdgcn_s_setprio(1);                                             \
    _Pragma("unroll") for (int ni = 0; ni < 4; ++ni) {                         \
      acc[2 * (p_)][ni] = mfma16(A0_, bfr[ni][0], acc[2 * (p_)][ni]);          \
      acc[2 * (p_)][ni] = mfma16(A1_, bfr[ni][1], acc[2 * (p_)][ni]);          \
      acc[2 * (p_) + 1][ni] = mfma16(A2_, bfr[ni][0], acc[2 * (p_) + 1][ni]);  \
      acc[2 * (p_) + 1][ni] = mfma16(A3_, bfr[ni][1], acc[2 * (p_) + 1][ni]);  \
    }                                                                          \
    __builtin_amdgcn_s_setprio(0);

    {
#pragma unroll
      for (int ni = 0; ni < 4; ++ni) {
        bfr[ni][0] = *(const bf16x8*)&Bc[b_row + ni * 1024 + sl0];
        bfr[ni][1] = *(const bf16x8*)&Bc[b_row + ni * 1024 + sl1];
      }
      bf16x8 f0 = *(const bf16x8*)&Ac[a_row + 0 * 1024 + sl0];
      bf16x8 f1 = *(const bf16x8*)&Ac[a_row + 0 * 1024 + sl1];
      bf16x8 f2 = *(const bf16x8*)&Ac[a_row + 1 * 1024 + sl0];
      bf16x8 f3 = *(const bf16x8*)&Ac[a_row + 1 * 1024 + sl1];
      if (s1ok) STAGE_HALF(a0s0, a0s1, &As_[alt][0], v + 1);
      BARRIER();
      MFMA_QUAD(0, f0, f1, f2, f3);
      BARRIER();
    }
    {
      bf16x8 f0 = *(const bf16x8*)&Ac[a_row + 2 * 1024 + sl0];
      bf16x8 f1 = *(const bf16x8*)&Ac[a_row + 2 * 1024 + sl1];
      bf16x8 f2 = *(const bf16x8*)&Ac[a_row + 3 * 1024 + sl0];
      bf16x8 f3 = *(const bf16x8*)&Ac[a_row + 3 * 1024 + sl1];
      if (s1ok) STAGE_HALF(a1s0, a1s1, &As_[alt][8192], v + 1);
      if (s2ok) STAGE_HALF(b0s0, b0s1, &Bs_[cur][0], v + 2);
      BARRIER();
      MFMA_QUAD(1, f0, f1, f2, f3);
      BARRIER();
    }
    {
      bf16x8 f0 = *(const bf16x8*)&Ac[a_row + 4 * 1024 + sl0];
      bf16x8 f1 = *(const bf16x8*)&Ac[a_row + 4 * 1024 + sl1];
      bf16x8 f2 = *(const bf16x8*)&Ac[a_row + 5 * 1024 + sl0];
      bf16x8 f3 = *(const bf16x8*)&Ac[a_row + 5 * 1024 + sl1];
      if (s2ok) STAGE_HALF(b1s0, b1s1, &Bs_[cur][8192], v + 2);
      BARRIER();
      MFMA_QUAD(2, f0, f1, f2, f3);
      BARRIER();
    }
    {
      bf16x8 f0 = *(const bf16x8*)&Ac[a_row + 6 * 1024 + sl0];
      bf16x8 f1 = *(const bf16x8*)&Ac[a_row + 6 * 1024 + sl1];
      bf16x8 f2 = *(const bf16x8*)&Ac[a_row + 7 * 1024 + sl0];
      bf16x8 f3 = *(const bf16x8*)&Ac[a_row + 7 * 1024 + sl1];
      BARRIER();
      MFMA_QUAD(3, f0, f1, f2, f3);
      if (s2ok) { WAITBAR(4); } else { WAITBAR(0); }
    }
#undef MFMA_QUAD
  }

#pragma unroll
  for (int mi = 0; mi < 8; ++mi)
#pragma unroll
    for (int ni = 0; ni < 4; ++ni)
#pragma unroll
      for (int r = 0; r < 4; ++r) {
        int row = bm + wr * 128 + mi * 16 + lg * 4 + r;
        int col = bn + wc * 64 + ni * 16 + l15;
        storeC(&C[(size_t)row * N + col], acc[mi][ni][r]);
      }
#undef STAGE_HALF
#undef WAITBAR
#undef BARRIER
}

// ---------------- split-K reduce: out += part ----------------
__global__ void reduce_add(float* __restrict__ out, const float* __restrict__ part, int n4) {
  int i = blockIdx.x * blockDim.x + threadIdx.x;
  int stride = gridDim.x * blockDim.x;
  for (; i < n4; i += stride) {
    float4 a = ((const float4*)out)[i];
    float4 b = ((const float4*)part)[i];
    a.x += b.x; a.y += b.y; a.z += b.z; a.w += b.w;
    ((float4*)out)[i] = a;
  }
}

// ---------------- causal GQA flash attention (R9-verified) + Wo-cvt tail ----
// blocks 0..511: attention (unchanged). blocks 512..575: fp32->bf16 convert of
// Wo (fills the tail; wo_bf consumed only by the later Wo GEMM).
__global__ void __launch_bounds__(256, 2)
attn_kernel(const u16* __restrict__ qkv, const u16* __restrict__ vt,
            u16* __restrict__ out,
            const float* __restrict__ cvt_in, u16* __restrict__ cvt_out,
            int cvt_n4) {
  if ((int)blockIdx.x >= 512) {
    int i = (blockIdx.x - 512) * blockDim.x + threadIdx.x;
    int stride = 64 * blockDim.x;
    for (; i < cvt_n4; i += stride) {
      float4 v = ((const float4*)cvt_in)[i];
      u16x4 o;
      o.x = f2bf(v.x); o.y = f2bf(v.y); o.z = f2bf(v.z); o.w = f2bf(v.w);
      ((u16x4*)cvt_out)[i] = o;
    }
    return;
  }

  __shared__ u16 Ksh[2][64 * 128];
  __shared__ u16 Vsh[2][128 * 64];

  const int tid = threadIdx.x;
  const int lane = tid & 63;
  const int w = tid >> 6;
  const int l15 = lane & 15, lg = lane >> 4;

  const int bid = blockIdx.x;
  const int u8 = bid & 255, sfl = bid >> 8;
  const int kvh = u8 & 7;
  const int hg = (u8 >> 3) & 3;
  const int x = (u8 >> 5) & 7;
  const int qi = sfl ? x : (15 - x);
  const int h = kvh * 4 + hg;
  const int q0 = qi * 128;
  const int nt = 2 * qi + 2;
  const int wrow = q0 + w * 32;

  const u16* Kg = qkv + NHEAD * HDIM + kvh * HDIM;
  const u16* Vg = vt + (size_t)kvh * HDIM * T_SEQ;

  bf16x8 qa[2][4];
#pragma unroll
  for (int mi = 0; mi < 2; ++mi) {
    const u16* qrow = qkv + (size_t)(wrow + mi * 16 + l15) * QKVN + h * HDIM + lg * 8;
#pragma unroll
    for (int ks = 0; ks < 4; ++ks) qa[mi][ks] = *(const bf16x8*)(qrow + ks * 32);
  }

  f32x4 acc_o[2][8] = {};
  float m[2] = {-1e30f, -1e30f}, lsum[2] = {0.f, 0.f};

  const float scale = 0.088388347648318447f;

#define STAGE_K(kv0, p)                                                        \
  {                                                                            \
    _Pragma("unroll") for (int rnd = 0; rnd < 4; ++rnd) {                      \
      int cc = rnd * 256 + tid;                                                \
      int krow = cc >> 4, kslot = cc & 15;                                     \
      gload16(Kg + (size_t)((kv0) + krow) * QKVN + (kslot ^ (krow & 7)) * 8,   \
              &Ksh[p][(rnd * 256 + w * 64) * 8]);                              \
    }                                                                          \
  }
#define STAGE_V(kv0, p)                                                        \
  {                                                                            \
    _Pragma("unroll") for (int rnd = 0; rnd < 4; ++rnd) {                      \
      int cc = rnd * 256 + tid;                                                \
      int vrow = cc >> 3, ps = cc & 7;                                         \
      gload16(Vg + (size_t)vrow * T_SEQ + (kv0) + ((ps ^ (vrow & 7)) * 8),     \
              &Vsh[p][(rnd * 256 + w * 64) * 8]);                              \
    }                                                                          \
  }

  STAGE_K(0, 0);
  STAGE_V(0, 0);
  __syncthreads();

  for (int t = 0; t < nt; ++t) {
    const int p = t & 1;
    const int kv0 = t * 64;
    const bool more = (t + 1 < nt);
    if (more) {
      STAGE_K(kv0 + 64, p ^ 1);
      STAGE_V(kv0 + 64, p ^ 1);
    }

    if (kv0 <= wrow + 31) {
      f32x4 s[2][4] = {};
#pragma unroll
      for (int ks = 0; ks < 4; ++ks) {
#pragma unroll
        for (int n = 0; n < 4; ++n) {
          int row16 = n * 16 + l15;
          bf16x8 kf = *(const bf16x8*)&Ksh[p][row16 * 128 +
                                              (((ks * 4 + lg) ^ (row16 & 7)) * 8)];
          s[0][n] = mfma16(kf, qa[0][ks], s[0][n]);
          s[1][n] = mfma16(kf, qa[1][ks], s[1][n]);
        }
      }

      const bool diag = (kv0 + 63 > wrow);
      float mx[2];
#pragma unroll
      for (int mi = 0; mi < 2; ++mi) {
        float mm = -1e30f;
        int tq = wrow + mi * 16 + l15;
#pragma unroll
        for (int n = 0; n < 4; ++n)
#pragma unroll
          for (int r = 0; r < 4; ++r) {
            float v = s[mi][n][r] * scale;
            if (diag && (kv0 + n * 16 + lg * 4 + r) > tq) v = -1e30f;
            s[mi][n][r] = v;
            mm = fmaxf(mm, v);
          }
        mm = fmaxf(mm, __shfl_xor(mm, 16, 64));
        mm = fmaxf(mm, __shfl_xor(mm, 32, 64));
        mx[mi] = mm;
      }

      float alpha[2];
#pragma unroll
      for (int mi = 0; mi < 2; ++mi) {
        float mn = fmaxf(m[mi], mx[mi]);
        alpha[mi] = __expf(m[mi] - mn);
        m[mi] = mn;
        lsum[mi] *= alpha[mi];
      }
#pragma unroll
      for (int mi = 0; mi < 2; ++mi)
#pragma unroll
        for (int r = 0; r < 4; ++r) {
          float al = __shfl(alpha[mi], lg * 4 + r, 64);
#pragma unroll
          for (int nd = 0; nd < 8; ++nd) acc_o[mi][nd][r] *= al;
        }

      bf16x8 paf[2][2];
#pragma unroll
      for (int mi = 0; mi < 2; ++mi) {
        float ps = 0.f;
#pragma unroll
        for (int n = 0; n < 4; ++n)
#pragma unroll
          for (int r = 0; r < 4; ++r) {
            float pv = __expf(s[mi][n][r] - m[mi]);
            s[mi][n][r] = pv;
            ps += pv;
          }
        ps += __shfl_xor(ps, 16, 64);
        ps += __shfl_xor(ps, 32, 64);
        lsum[mi] += ps;
#pragma unroll
        for (int ks = 0; ks < 2; ++ks) {
          u16x8 pk;
#pragma unroll
          for (int hn = 0; hn < 2; ++hn)
#pragma unroll
            for (int r = 0; r < 4; ++r)
              pk[hn * 4 + r] = f2bf(s[mi][2 * ks + hn][r]);
          paf[mi][ks] = __builtin_bit_cast(bf16x8, pk);
        }
      }

#pragma unroll
      for (int ks = 0; ks < 2; ++ks) {
#pragma unroll
        for (int nd = 0; nd < 8; ++nd) {
          int d = nd * 16 + l15;
          bf16x8 bv = *(const bf16x8*)&Vsh[p][d * 64 + (((ks * 4 + lg) ^ (d & 7)) * 8)];
          acc_o[0][nd] = mfma16(paf[0][ks], bv, acc_o[0][nd]);
          acc_o[1][nd] = mfma16(paf[1][ks], bv, acc_o[1][nd]);
        }
      }
    }

    __syncthreads();
  }

#pragma unroll
  for (int mi = 0; mi < 2; ++mi)
#pragma unroll
    for (int r = 0; r < 4; ++r) {
      float ls = __shfl(lsum[mi], lg * 4 + r, 64);
      float inv = 1.f / ls;
      int row = wrow + mi * 16 + lg * 4 + r;
#pragma unroll
      for (int nd = 0; nd < 8; ++nd) {
        int col = h * HDIM + nd * 16 + l15;
        out[(size_t)row * (NHEAD * HDIM) + col] = f2bf(acc_o[mi][nd][r] * inv);
      }
    }
#undef STAGE_K
#undef STAGE_V
}

// ---------------- launcher ----------------
extern "C" void kernel_launch(void* const* d_in, const int* in_sizes, int n_in,
                              void* d_out, int out_size, void* d_ws, size_t ws_size,
                              hipStream_t stream) {
  const float* hs   = (const float*)d_in[0];
  const int*   pos  = (const int*)d_in[1];
  const float* wqkv = (const float*)d_in[2];
  const float* wo   = (const float*)d_in[3];
  float* out = (float*)d_out;
  uint8_t* ws = (uint8_t*)d_ws;

  if (ws_size < 142606336u) return;
  u16* hs_bf   = (u16*)(ws + 0);
  u16* wqkv_bf = (u16*)(ws + 16777216u);
  u16* wo_bf   = (u16*)(ws + 67108864u);
  u16* qkv_bf  = (u16*)(ws + 100663296u);
  u16* attn_bf = (u16*)(ws + 125829120u);
  float* part  = (float*)(ws + 16777216u);  // reuse wqkv_bf (dead after QKV GEMM)
  u16* vt_buf  = (u16*)(ws + 0);            // reuse hs_bf (dead after QKV GEMM)

  cvt_f32_bf16<<<2048, 256, 0, stream>>>(hs, hs_bf, T_SEQ * HIDDEN);
  cvt_f32_bf16<<<2048, 256, 0, stream>>>(wqkv, wqkv_bf, QKVN * HIDDEN);

  // QKV: 128x384 tiles -> 16 x 16 = 256 blocks, exact machine fill
  gemm_qkv<<<256, 512, 0, stream>>>(hs_bf, wqkv_bf, qkv_bf, T_SEQ, QKVN, HIDDEN);

  rope_kernel<<<(T_SEQ * 40 * 64) / 256, 256, 0, stream>>>(qkv_bf, pos);

  vt_kernel<<<dim3(32, 16), 256, 0, stream>>>(qkv_bf, vt_buf);

  // attn (512 blocks) + Wo fp32->bf16 convert riding the tail (64 blocks)
  attn_kernel<<<576, 256, 0, stream>>>(qkv_bf, vt_buf, attn_bf,
                                       wo, wo_bf, (HIDDEN * HIDDEN) / 4);

  // Wo: split-K=2, 2 x (8x16) = 256 blocks exact fill; slice1 -> part buffer
  gemm256<float><<<256, 512, 0, stream>>>(
      attn_bf, wo_bf, out, part, HIDDEN, HIDDEN, 32, 128, 16, 2, 8);

  reduce_add<<<2048, 256, 0, stream>>>(out, part, (T_SEQ * HIDDEN) / 4);
}

// Round 11
// 317.728 us; speedup vs baseline: 1.2172x; 1.2172x over previous
//
#include <hip/hip_runtime.h>
#include <stdint.h>

#define T_SEQ 2048
#define HIDDEN 4096
#define NHEAD 32
#define NKV 8
#define HDIM 128
#define QKVN 6144  // (32 + 2*8) * 128

typedef __bf16 bf16x8 __attribute__((ext_vector_type(8)));
typedef float f32x4 __attribute__((ext_vector_type(4)));
typedef unsigned short u16;
typedef u16 u16x8 __attribute__((ext_vector_type(8)));
typedef u16 u16x4 __attribute__((ext_vector_type(4)));

__device__ __forceinline__ u16 f2bf(float f) {
  uint32_t u = __builtin_bit_cast(uint32_t, f);
  u = (u + 0x7fffu + ((u >> 16) & 1u)) >> 16;
  return (u16)u;
}
__device__ __forceinline__ float bf2f(u16 h) {
  uint32_t u = ((uint32_t)h) << 16;
  return __builtin_bit_cast(float, u);
}

// async global->LDS, 16B per lane. LDS dest must be wave-uniform; HW adds lane*16.
__device__ __forceinline__ void gload16(const void* g, void* l) {
  __builtin_amdgcn_global_load_lds(
      (__attribute__((address_space(1))) void*)(uintptr_t)g,
      (__attribute__((address_space(3))) void*)(uintptr_t)l, 16, 0, 0);
}

// ---------------- fused fp32 -> bf16 convert of hs + wqkv ----------------
__global__ void cvt2_kernel(const float* __restrict__ in1, u16* __restrict__ out1, int n1_4,
                            const float* __restrict__ in2, u16* __restrict__ out2, int n2_4) {
  int base = blockIdx.x * blockDim.x + threadIdx.x;
  int stride = gridDim.x * blockDim.x;
  for (int i = base; i < n1_4; i += stride) {
    float4 v = ((const float4*)in1)[i];
    u16x4 o;
    o.x = f2bf(v.x); o.y = f2bf(v.y); o.z = f2bf(v.z); o.w = f2bf(v.w);
    ((u16x4*)out1)[i] = o;
  }
  for (int i = base; i < n2_4; i += stride) {
    float4 v = ((const float4*)in2)[i];
    u16x4 o;
    o.x = f2bf(v.x); o.y = f2bf(v.y); o.z = f2bf(v.z); o.w = f2bf(v.w);
    ((u16x4*)out2)[i] = o;
  }
}

// ---- merged prep: blocks 0..511 = V^T transpose; 512.. = RoPE + cvt(Wo) ----
// vt[kvh][d][64-block base + c] holds V[base + kv(c)][d], where
// kv(c) = 32*(c>>5) + 16*((c>>2)&1) + 4*((c>>3)&3) + (c&3).
// RoPE touches Q/K columns only; vt reads V columns only -> concurrent-safe.
__global__ void prep_kernel(u16* __restrict__ qkv, const int* __restrict__ pos,
                            u16* __restrict__ vt,
                            const float* __restrict__ wo_in, u16* __restrict__ wo_out,
                            int wo_n4) {
  __shared__ u16 tile[64][64];
  const int bid = blockIdx.x;
  const int tid = threadIdx.x;

  if (bid < 512) {
    const int tb = bid & 31;
    const int yy = bid >> 5;          // 0..15
    const int kvh = yy >> 1;
    const int d0 = (yy & 1) * 64;
    const u16* src = qkv + (size_t)(NHEAD + NKV) * HDIM + kvh * HDIM + d0;
#pragma unroll
    for (int g = 0; g < 2; ++g) {
      int u = g * 256 + tid;
      int t = u >> 3, ds = u & 7;
      u16x8 v = *(const u16x8*)(src + (size_t)(tb * 64 + t) * QKVN + ds * 8);
#pragma unroll
      for (int j = 0; j < 8; ++j) {
        int d = ds * 8 + j;
        tile[d][(((t >> 3) ^ (d & 7)) * 8) + (t & 7)] = v[j];
      }
    }
    __syncthreads();
    u16* dst = vt + ((size_t)kvh * HDIM + d0) * T_SEQ + tb * 64;
#pragma unroll
    for (int g = 0; g < 4; ++g) {
      int u = g * 256 + tid;
      int d = u >> 4, qd = u & 15;
      int a = qd >> 3, gg = (qd >> 1) & 3, b = qd & 1;
      int t0 = 32 * a + 16 * b + 4 * gg;
      u16x4 v = *(const u16x4*)&tile[d][(((t0 >> 3) ^ (d & 7)) * 8) + (t0 & 7)];
      *(u16x4*)(dst + (size_t)d * T_SEQ + qd * 4) = v;
    }
    return;
  }

  // RoPE (grid-stride over T*40*64 pairs), then Wo fp32->bf16 (grid-stride)
  const int nb = gridDim.x - 512;
  const int base = (bid - 512) * blockDim.x + tid;
  const int stride = nb * blockDim.x;
  for (int idx = base; idx < T_SEQ * 40 * 64; idx += stride) {
    int i = idx & 63;
    int head = (idx >> 6) % 40;
    int t = idx / (40 * 64);
    int hb = head < NHEAD ? head * HDIM : NHEAD * HDIM + (head - NHEAD) * HDIM;
    float p = (float)pos[t];
    float inv_freq = exp2f(-(float)i * (13.287712379549449f / 64.0f));
    float ang = p * inv_freq;
    float s, c;
    sincosf(ang, &s, &c);
    u16* p1 = qkv + (size_t)t * QKVN + hb + i;
    u16* p2 = p1 + 64;
    float x1 = bf2f(*p1), x2 = bf2f(*p2);
    *p1 = f2bf(x1 * c - x2 * s);
    *p2 = f2bf(x2 * c + x1 * s);
  }
  for (int i = base; i < wo_n4; i += stride) {
    float4 v = ((const float4*)wo_in)[i];
    u16x4 o;
    o.x = f2bf(v.x); o.y = f2bf(v.y); o.z = f2bf(v.z); o.w = f2bf(v.w);
    ((u16x4*)wo_out)[i] = o;
  }
}

__device__ __forceinline__ void storeC(float* p, float v) { *p = v; }
__device__ __forceinline__ void storeC(u16* p, float v) { *p = f2bf(v); }
__device__ __forceinline__ f32x4 mfma16(bf16x8 a, bf16x8 b, f32x4 c) {
  return __builtin_amdgcn_mfma_f32_16x16x32_bf16(a, b, c, 0, 0, 0);
}

// -------- QKV GEMM: 128x384 tiles, 16x16 = 256 blocks (exact fill), BK=64 ---
__global__ void __launch_bounds__(512, 1)
gemm_qkv(const u16* __restrict__ A, const u16* __restrict__ B,
         u16* __restrict__ C, int M, int N, int K) {
  __shared__ u16 As_[2][128 * 64];
  __shared__ u16 Bs_[2][384 * 64];

  const int tid = threadIdx.x;
  const int lane = tid & 63;
  const int w = tid >> 6;
  const int wr = w >> 2, wc = w & 3;   // 2M x 4N, per-wave 64x96
  const int l15 = lane & 15, lg = lane >> 4;

  const int c8 = blockIdx.x & 7, i8 = blockIdx.x >> 3;
  const int by = i8 & 15;
  const int bx = c8 * 2 + (i8 >> 4);
  const int bm = by * 128, bn = bx * 384;

  const int u_lo = w * 64 + lane, u_hi = u_lo + 512;
  const int r0 = u_lo >> 3, s0 = (u_lo & 7) ^ (r0 & 7);
  const int r1 = u_hi >> 3, s1 = (u_hi & 7) ^ (r1 & 7);
  const u16* a_s0 = A + (size_t)(bm + r0) * K + s0 * 8;
  const u16* a_s1 = A + (size_t)(bm + r1) * K + s1 * 8;
  const u16* b_s0[3];
  const u16* b_s1[3];
#pragma unroll
  for (int h = 0; h < 3; ++h) {
    b_s0[h] = B + (size_t)(bn + h * 128 + r0) * K + s0 * 8;
    b_s1[h] = B + (size_t)(bn + h * 128 + r1) * K + s1 * 8;
  }

  const int ax = l15 & 7;
  const int sl0 = (lg ^ ax) * 8;
  const int sl1 = ((4 + lg) ^ ax) * 8;
  const int a_row = (wr * 64 + l15) * 64;
  const int b_row = (wc * 96 + l15) * 64;

  f32x4 acc[4][6] = {};
  bf16x8 bfr[6][2];

#define BARRIER() asm volatile("s_barrier" ::: "memory")
#define WAITBAR(n_) asm volatile("s_waitcnt vmcnt(" #n_ ")\n\ts_barrier" ::: "memory")
#define STAGE_A(t_, p_)                                                        \
  {                                                                            \
    gload16(a_s0 + (size_t)(t_) * 64, &As_[p_][w * 512]);                      \
    gload16(a_s1 + (size_t)(t_) * 64, &As_[p_][4096 + w * 512]);               \
  }
#define STAGE_B(t_, p_, h_)                                                    \
  {                                                                            \
    gload16(b_s0[h_] + (size_t)(t_) * 64, &Bs_[p_][(h_) * 8192 + w * 512]);    \
    gload16(b_s1[h_] + (size_t)(t_) * 64,                                      \
            &Bs_[p_][(h_) * 8192 + 4096 + w * 512]);                           \
  }

  STAGE_A(0, 0);
  STAGE_B(0, 0, 0); STAGE_B(0, 0, 1); STAGE_B(0, 0, 2);
  STAGE_B(1, 1, 0); STAGE_B(1, 1, 1); STAGE_B(1, 1, 2);
  WAITBAR(6);

  const int NT = K >> 6;
  for (int v = 0; v < NT; ++v) {
    const int cur = v & 1, alt = cur ^ 1;
    const u16* Ac = &As_[cur][0];
    const u16* Bc = &Bs_[cur][0];
    const bool s1ok = (v + 1) < NT, s2ok = (v + 2) < NT;

#define MFMA_PH(mi_, A0_, A1_)                                                 \
    __builtin_amdgcn_s_setprio(1);                                             \
    _Pragma("unroll") for (int ni = 0; ni < 6; ++ni) {                         \
      acc[mi_][ni] = mfma16(A0_, bfr[ni][0], acc[mi_][ni]);                    \
      acc[mi_][ni] = mfma16(A1_, bfr[ni][1], acc[mi_][ni]);                    \
    }                                                                          \
    __builtin_amdgcn_s_setprio(0);

    {
      if (s1ok) STAGE_A(v + 1, alt);
#pragma unroll
      for (int ni = 0; ni < 6; ++ni) {
        bfr[ni][0] = *(const bf16x8*)&Bc[b_row + ni * 1024 + sl0];
        bfr[ni][1] = *(const bf16x8*)&Bc[b_row + ni * 1024 + sl1];
      }
      bf16x8 a0 = *(const bf16x8*)&Ac[a_row + 0 * 1024 + sl0];
      bf16x8 a1 = *(const bf16x8*)&Ac[a_row + 0 * 1024 + sl1];
      BARRIER();
      MFMA_PH(0, a0, a1);
      BARRIER();
    }
    {
      if (s2ok) STAGE_B(v + 2, cur, 0);
      bf16x8 a0 = *(const bf16x8*)&Ac[a_row + 1 * 1024 + sl0];
      bf16x8 a1 = *(const bf16x8*)&Ac[a_row + 1 * 1024 + sl1];
      BARRIER();
      MFMA_PH(1, a0, a1);
      BARRIER();
    }
    {
      if (s2ok) STAGE_B(v + 2, cur, 1);
      bf16x8 a0 = *(const bf16x8*)&Ac[a_row + 2 * 1024 + sl0];
      bf16x8 a1 = *(const bf16x8*)&Ac[a_row + 2 * 1024 + sl1];
      BARRIER();
      MFMA_PH(2, a0, a1);
      BARRIER();
    }
    {
      if (s2ok) STAGE_B(v + 2, cur, 2);
      bf16x8 a0 = *(const bf16x8*)&Ac[a_row + 3 * 1024 + sl0];
      bf16x8 a1 = *(const bf16x8*)&Ac[a_row + 3 * 1024 + sl1];
      BARRIER();
      MFMA_PH(3, a0, a1);
      if (s2ok) { WAITBAR(6); } else if (s1ok) { WAITBAR(0); } else { BARRIER(); }
    }
#undef MFMA_PH
  }

#pragma unroll
  for (int mi = 0; mi < 4; ++mi)
#pragma unroll
    for (int ni = 0; ni < 6; ++ni)
#pragma unroll
      for (int r = 0; r < 4; ++r) {
        int row = bm + wr * 64 + mi * 16 + lg * 4 + r;
        int col = bn + wc * 96 + ni * 16 + l15;
        storeC(&C[(size_t)row * N + col], acc[mi][ni][r]);
      }
#undef STAGE_A
#undef STAGE_B
#undef WAITBAR
#undef BARRIER
}

// -------- 256x256 NT GEMM (Wo, split-K) ------------------
template <typename OutT>
__global__ void __launch_bounds__(512, 2)
gemm256(const u16* __restrict__ A, const u16* __restrict__ B,
        OutT* __restrict__ C0, OutT* __restrict__ C1,
        int N, int K, int NT, int sliceBlocks,
        int nbx, int rw, int rh) {
  __shared__ u16 As_[2][256 * 64];
  __shared__ u16 Bs_[2][256 * 64];

  const int tid = threadIdx.x;
  const int lane = tid & 63;
  const int w = tid >> 6;
  const int wr = w >> 2, wc = w & 3;
  const int l15 = lane & 15, lg = lane >> 4;

  const int bid = blockIdx.x;
  const int slice = bid / sliceBlocks;
  const int wi = bid % sliceBlocks;
  const int k0 = slice * (NT << 6);
  OutT* __restrict__ C = slice ? C1 : C0;

  const int c8 = wi & 7, i8 = wi >> 3;
  const int rpr = nbx / rw;
  const int by = (c8 / rpr) * rh + (i8 % rh);
  const int bx = (c8 % rpr) * rw + (i8 / rh);
  const int bm = by * 256, bn = bx * 256;

  const int u_lo = w * 64 + lane, u_hi = u_lo + 512;
  const int r0 = u_lo >> 3, s0 = (u_lo & 7) ^ (r0 & 7);
  const int r1 = u_hi >> 3, s1 = (u_hi & 7) ^ (r1 & 7);
  const u16* a0s0 = A + (size_t)(bm + r0) * K + k0 + s0 * 8;
  const u16* a0s1 = A + (size_t)(bm + r1) * K + k0 + s1 * 8;
  const u16* a1s0 = A + (size_t)(bm + 128 + r0) * K + k0 + s0 * 8;
  const u16* a1s1 = A + (size_t)(bm + 128 + r1) * K + k0 + s1 * 8;
  const u16* b0s0 = B + (size_t)(bn + r0) * K + k0 + s0 * 8;
  const u16* b0s1 = B + (size_t)(bn + r1) * K + k0 + s1 * 8;
  const u16* b1s0 = B + (size_t)(bn + 128 + r0) * K + k0 + s0 * 8;
  const u16* b1s1 = B + (size_t)(bn + 128 + r1) * K + k0 + s1 * 8;

  const int ax = l15 & 7;
  const int sl0 = (lg ^ ax) * 8;
  const int sl1 = ((4 + lg) ^ ax) * 8;
  const int a_row = (wr * 128 + l15) * 64;
  const int b_row = (wc * 64 + l15) * 64;

  f32x4 acc[8][4] = {};
  bf16x8 bfr[4][2];

#define BARRIER() asm volatile("s_barrier" ::: "memory")
#define WAITBAR(n_) asm volatile("s_waitcnt vmcnt(" #n_ ")\n\ts_barrier" ::: "memory")
#define STAGE_HALF(p0_, p1_, dst_, t_)                                         \
  {                                                                            \
    gload16((p0_) + (size_t)(t_) * 64, (dst_) + (size_t)w * 512);              \
    gload16((p1_) + (size_t)(t_) * 64, (dst_) + 4096 + (size_t)w * 512);       \
  }

  STAGE_HALF(a0s0, a0s1, &As_[0][0], 0);
  STAGE_HALF(a1s0, a1s1, &As_[0][8192], 0);
  STAGE_HALF(b0s0, b0s1, &Bs_[0][0], 0);
  STAGE_HALF(b1s0, b1s1, &Bs_[0][8192], 0);
  STAGE_HALF(b0s0, b0s1, &Bs_[1][0], 1);
  STAGE_HALF(b1s0, b1s1, &Bs_[1][8192], 1);
  WAITBAR(4);

  for (int v = 0; v < NT; ++v) {
    const int cur = v & 1, alt = cur ^ 1;
    const u16* Ac = &As_[cur][0];
    const u16* Bc = &Bs_[cur][0];
    const bool s1ok = (v + 1) < NT, s2ok = (v + 2) < NT;

#define MFMA_QUAD(p_, A0_, A1_, A2_, A3_)                                      \
    __builtin_amdgcn_s_setprio(1);                                             \
    _Pragma("unroll") for (int ni = 0; ni < 4; ++ni) {                         \
      acc[2 * (p_)][ni] = mfma16(A0_, bfr[ni][0], acc[2 * (p_)][ni]);          \
      acc[2 * (p_)][ni] = mfma16(A1_, bfr[ni][1], acc[2 * (p_)][ni]);          \
      acc[2 * (p_) + 1][ni] = mfma16(A2_, bfr[ni][0], acc[2 * (p_) + 1][ni]);  \
      acc[2 * (p_) + 1][ni] = mfma16(A3_, bfr[ni][1], acc[2 * (p_) + 1][ni]);  \
    }                                                                          \
    __builtin_amdgcn_s_setprio(0);

    {
#pragma unroll
      for (int ni = 0; ni < 4; ++ni) {
        bfr[ni][0] = *(const bf16x8*)&Bc[b_row + ni * 1024 + sl0];
        bfr[ni][1] = *(const bf16x8*)&Bc[b_row + ni * 1024 + sl1];
      }
      bf16x8 f0 = *(const bf16x8*)&Ac[a_row + 0 * 1024 + sl0];
      bf16x8 f1 = *(const bf16x8*)&Ac[a_row + 0 * 1024 + sl1];
      bf16x8 f2 = *(const bf16x8*)&Ac[a_row + 1 * 1024 + sl0];
      bf16x8 f3 = *(const bf16x8*)&Ac[a_row + 1 * 1024 + sl1];
      if (s1ok) STAGE_HALF(a0s0, a0s1, &As_[alt][0], v + 1);
      BARRIER();
      MFMA_QUAD(0, f0, f1, f2, f3);
      BARRIER();
    }
    {
      bf16x8 f0 = *(const bf16x8*)&Ac[a_row + 2 * 1024 + sl0];
      bf16x8 f1 = *(const bf16x8*)&Ac[a_row + 2 * 1024 + sl1];
      bf16x8 f2 = *(const bf16x8*)&Ac[a_row + 3 * 1024 + sl0];
      bf16x8 f3 = *(const bf16x8*)&Ac[a_row + 3 * 1024 + sl1];
      if (s1ok) STAGE_HALF(a1s0, a1s1, &As_[alt][8192], v + 1);
      if (s2ok) STAGE_HALF(b0s0, b0s1, &Bs_[cur][0], v + 2);
      BARRIER();
      MFMA_QUAD(1, f0, f1, f2, f3);
      BARRIER();
    }
    {
      bf16x8 f0 = *(const bf16x8*)&Ac[a_row + 4 * 1024 + sl0];
      bf16x8 f1 = *(const bf16x8*)&Ac[a_row + 4 * 1024 + sl1];
      bf16x8 f2 = *(const bf16x8*)&Ac[a_row + 5 * 1024 + sl0];
      bf16x8 f3 = *(const bf16x8*)&Ac[a_row + 5 * 1024 + sl1];
      if (s2ok) STAGE_HALF(b1s0, b1s1, &Bs_[cur][8192], v + 2);
      BARRIER();
      MFMA_QUAD(2, f0, f1, f2, f3);
      BARRIER();
    }
    {
      bf16x8 f0 = *(const bf16x8*)&Ac[a_row + 6 * 1024 + sl0];
      bf16x8 f1 = *(const bf16x8*)&Ac[a_row + 6 * 1024 + sl1];
      bf16x8 f2 = *(const bf16x8*)&Ac[a_row + 7 * 1024 + sl0];
      bf16x8 f3 = *(const bf16x8*)&Ac[a_row + 7 * 1024 + sl1];
      BARRIER();
      MFMA_QUAD(3, f0, f1, f2, f3);
      if (s2ok) { WAITBAR(4); } else { WAITBAR(0); }
    }
#undef MFMA_QUAD
  }

#pragma unroll
  for (int mi = 0; mi < 8; ++mi)
#pragma unroll
    for (int ni = 0; ni < 4; ++ni)
#pragma unroll
      for (int r = 0; r < 4; ++r) {
        int row = bm + wr * 128 + mi * 16 + lg * 4 + r;
        int col = bn + wc * 64 + ni * 16 + l15;
        storeC(&C[(size_t)row * N + col], acc[mi][ni][r]);
      }
#undef STAGE_HALF
#undef WAITBAR
#undef BARRIER
}

// ---------------- split-K reduce: out += part ----------------
__global__ void reduce_add(float* __restrict__ out, const float* __restrict__ part, int n4) {
  int i = blockIdx.x * blockDim.x + threadIdx.x;
  int stride = gridDim.x * blockDim.x;
  for (; i < n4; i += stride) {
    float4 a = ((const float4*)out)[i];
    float4 b = ((const float4*)part)[i];
    a.x += b.x; a.y += b.y; a.z += b.z; a.w += b.w;
    ((float4*)out)[i] = a;
  }
}

// ---------------- causal GQA flash attention (R9-verified, 512 blocks) ------
__global__ void __launch_bounds__(256, 2)
attn_kernel(const u16* __restrict__ qkv, const u16* __restrict__ vt,
            u16* __restrict__ out) {
  __shared__ u16 Ksh[2][64 * 128];
  __shared__ u16 Vsh[2][128 * 64];

  const int tid = threadIdx.x;
  const int lane = tid & 63;
  const int w = tid >> 6;
  const int l15 = lane & 15, lg = lane >> 4;

  const int bid = blockIdx.x;
  const int u8 = bid & 255, sfl = bid >> 8;
  const int kvh = u8 & 7;
  const int hg = (u8 >> 3) & 3;
  const int x = (u8 >> 5) & 7;
  const int qi = sfl ? x : (15 - x);
  const int h = kvh * 4 + hg;
  const int q0 = qi * 128;
  const int nt = 2 * qi + 2;
  const int wrow = q0 + w * 32;

  const u16* Kg = qkv + NHEAD * HDIM + kvh * HDIM;
  const u16* Vg = vt + (size_t)kvh * HDIM * T_SEQ;

  bf16x8 qa[2][4];
#pragma unroll
  for (int mi = 0; mi < 2; ++mi) {
    const u16* qrow = qkv + (size_t)(wrow + mi * 16 + l15) * QKVN + h * HDIM + lg * 8;
#pragma unroll
    for (int ks = 0; ks < 4; ++ks) qa[mi][ks] = *(const bf16x8*)(qrow + ks * 32);
  }

  f32x4 acc_o[2][8] = {};
  float m[2] = {-1e30f, -1e30f}, lsum[2] = {0.f, 0.f};

  const float scale = 0.088388347648318447f;

#define STAGE_K(kv0, p)                                                        \
  {                                                                            \
    _Pragma("unroll") for (int rnd = 0; rnd < 4; ++rnd) {                      \
      int cc = rnd * 256 + tid;                                                \
      int krow = cc >> 4, kslot = cc & 15;                                     \
      gload16(Kg + (size_t)((kv0) + krow) * QKVN + (kslot ^ (krow & 7)) * 8,   \
              &Ksh[p][(rnd * 256 + w * 64) * 8]);                              \
    }                                                                          \
  }
#define STAGE_V(kv0, p)                                                        \
  {                                                                            \
    _Pragma("unroll") for (int rnd = 0; rnd < 4; ++rnd) {                      \
      int cc = rnd * 256 + tid;                                                \
      int vrow = cc >> 3, ps = cc & 7;                                         \
      gload16(Vg + (size_t)vrow * T_SEQ + (kv0) + ((ps ^ (vrow & 7)) * 8),     \
              &Vsh[p][(rnd * 256 + w * 64) * 8]);                              \
    }                                                                          \
  }

  STAGE_K(0, 0);
  STAGE_V(0, 0);
  __syncthreads();

  for (int t = 0; t < nt; ++t) {
    const int p = t & 1;
    const int kv0 = t * 64;
    const bool more = (t + 1 < nt);
    if (more) {
      STAGE_K(kv0 + 64, p ^ 1);
      STAGE_V(kv0 + 64, p ^ 1);
    }

    if (kv0 <= wrow + 31) {
      f32x4 s[2][4] = {};
#pragma unroll
      for (int ks = 0; ks < 4; ++ks) {
#pragma unroll
        for (int n = 0; n < 4; ++n) {
          int row16 = n * 16 + l15;
          bf16x8 kf = *(const bf16x8*)&Ksh[p][row16 * 128 +
                                              (((ks * 4 + lg) ^ (row16 & 7)) * 8)];
          s[0][n] = mfma16(kf, qa[0][ks], s[0][n]);
          s[1][n] = mfma16(kf, qa[1][ks], s[1][n]);
        }
      }

      const bool diag = (kv0 + 63 > wrow);
      float mx[2];
#pragma unroll
      for (int mi = 0; mi < 2; ++mi) {
        float mm = -1e30f;
        int tq = wrow + mi * 16 + l15;
#pragma unroll
        for (int n = 0; n < 4; ++n)
#pragma unroll
          for (int r = 0; r < 4; ++r) {
            float v = s[mi][n][r] * scale;
            if (diag && (kv0 + n * 16 + lg * 4 + r) > tq) v = -1e30f;
            s[mi][n][r] = v;
            mm = fmaxf(mm, v);
          }
        mm = fmaxf(mm, __shfl_xor(mm, 16, 64));
        mm = fmaxf(mm, __shfl_xor(mm, 32, 64));
        mx[mi] = mm;
      }

      float alpha[2];
#pragma unroll
      for (int mi = 0; mi < 2; ++mi) {
        float mn = fmaxf(m[mi], mx[mi]);
        alpha[mi] = __expf(m[mi] - mn);
        m[mi] = mn;
        lsum[mi] *= alpha[mi];
      }
#pragma unroll
      for (int mi = 0; mi < 2; ++mi)
#pragma unroll
        for (int r = 0; r < 4; ++r) {
          float al = __shfl(alpha[mi], lg * 4 + r, 64);
#pragma unroll
          for (int nd = 0; nd < 8; ++nd) acc_o[mi][nd][r] *= al;
        }

      bf16x8 paf[2][2];
#pragma unroll
      for (int mi = 0; mi < 2; ++mi) {
        float ps = 0.f;
#pragma unroll
        for (int n = 0; n < 4; ++n)
#pragma unroll
          for (int r = 0; r < 4; ++r) {
            float pv = __expf(s[mi][n][r] - m[mi]);
            s[mi][n][r] = pv;
            ps += pv;
          }
        ps += __shfl_xor(ps, 16, 64);
        ps += __shfl_xor(ps, 32, 64);
        lsum[mi] += ps;
#pragma unroll
        for (int ks = 0; ks < 2; ++ks) {
          u16x8 pk;
#pragma unroll
          for (int hn = 0; hn < 2; ++hn)
#pragma unroll
            for (int r = 0; r < 4; ++r)
              pk[hn * 4 + r] = f2bf(s[mi][2 * ks + hn][r]);
          paf[mi][ks] = __builtin_bit_cast(bf16x8, pk);
        }
      }

#pragma unroll
      for (int ks = 0; ks < 2; ++ks) {
#pragma unroll
        for (int nd = 0; nd < 8; ++nd) {
          int d = nd * 16 + l15;
          bf16x8 bv = *(const bf16x8*)&Vsh[p][d * 64 + (((ks * 4 + lg) ^ (d & 7)) * 8)];
          acc_o[0][nd] = mfma16(paf[0][ks], bv, acc_o[0][nd]);
          acc_o[1][nd] = mfma16(paf[1][ks], bv, acc_o[1][nd]);
        }
      }
    }

    __syncthreads();
  }

#pragma unroll
  for (int mi = 0; mi < 2; ++mi)
#pragma unroll
    for (int r = 0; r < 4; ++r) {
      float ls = __shfl(lsum[mi], lg * 4 + r, 64);
      float inv = 1.f / ls;
      int row = wrow + mi * 16 + lg * 4 + r;
#pragma unroll
      for (int nd = 0; nd < 8; ++nd) {
        int col = h * HDIM + nd * 16 + l15;
        out[(size_t)row * (NHEAD * HDIM) + col] = f2bf(acc_o[mi][nd][r] * inv);
      }
    }
#undef STAGE_K
#undef STAGE_V
}

// ---------------- launcher ----------------
extern "C" void kernel_launch(void* const* d_in, const int* in_sizes, int n_in,
                              void* d_out, int out_size, void* d_ws, size_t ws_size,
                              hipStream_t stream) {
  const float* hs   = (const float*)d_in[0];
  const int*   pos  = (const int*)d_in[1];
  const float* wqkv = (const float*)d_in[2];
  const float* wo   = (const float*)d_in[3];
  float* out = (float*)d_out;
  uint8_t* ws = (uint8_t*)d_ws;

  if (ws_size < 142606336u) return;
  u16* hs_bf   = (u16*)(ws + 0);
  u16* wqkv_bf = (u16*)(ws + 16777216u);
  u16* wo_bf   = (u16*)(ws + 67108864u);
  u16* qkv_bf  = (u16*)(ws + 100663296u);
  u16* attn_bf = (u16*)(ws + 125829120u);
  float* part  = (float*)(ws + 16777216u);  // reuse wqkv_bf (dead after QKV GEMM)
  u16* vt_buf  = (u16*)(ws + 0);            // reuse hs_bf (dead after QKV GEMM)

  // hs + wqkv fp32->bf16, one launch
  cvt2_kernel<<<2048, 256, 0, stream>>>(hs, hs_bf, (T_SEQ * HIDDEN) / 4,
                                        wqkv, wqkv_bf, (QKVN * HIDDEN) / 4);

  // QKV: 128x384 tiles -> 16 x 16 = 256 blocks, exact machine fill
  gemm_qkv<<<256, 512, 0, stream>>>(hs_bf, wqkv_bf, qkv_bf, T_SEQ, QKVN, HIDDEN);

  // merged: V^T transpose (512 blocks) + RoPE + Wo cvt (1536 blocks), co-scheduled
  prep_kernel<<<2048, 256, 0, stream>>>(qkv_bf, pos, vt_buf,
                                        wo, wo_bf, (HIDDEN * HIDDEN) / 4);

  attn_kernel<<<512, 256, 0, stream>>>(qkv_bf, vt_buf, attn_bf);

  // Wo: split-K=2, 2 x (8x16) = 256 blocks exact fill; slice1 -> part buffer
  gemm256<float><<<256, 512, 0, stream>>>(
      attn_bf, wo_bf, out, part, HIDDEN, HIDDEN, 32, 128, 16, 2, 8);

  reduce_add<<<2048, 256, 0, stream>>>(out, part, (T_SEQ * HIDDEN) / 4);
}